// Round 4
// baseline (2075.121 us; speedup 1.0000x reference)
//
#include <hip/hip_runtime.h>

#define UNITS 32
#define NB 256
#define NT 1024
#define NUNF 6
#define L2E 1.44269504088896340736f

typedef const float* fp;

extern "C" __device__ float __ocml_exp2_f32(float);
__device__ __forceinline__ float frcp(float x) { return __builtin_amdgcn_rcpf(x); }
__device__ __forceinline__ float ex2(float x) { return __ocml_exp2_f32(x); }

// ws layout (bytes):
//   0     prc  int[32*8]    chain-slot pre lane id (stride 8)
//   1024  a2c  f[32*8]      -sigma*L2E
//   2048  b2c  f[32*8]      sigma*mu*L2E
//   3072  wc   f[32*8]      w
//   4096  ec   f[32*8]      w*erev
//   5120  pric int[32*12]   prep-slot inter index 0..11 (stride 12)
//   6656  a2i  f[32*12]
//   8192  b2i  f[32*12]
//   9728  wi   f[32*12]
//   11264 ei   f[32*12]
//   12800 maxc,maxic int[2]
//   16384 interState f[256*12]
//   32768 vstate f[256*32]
//   65536 sensC  float2[CT*256*32]   (pn' = gl*vl + wn_s ; pd' = 6cm+gl+eps + wd_s)
//   65536+CT*65536 interP float4[CT*256*12]  (vi0, A, B, 0)
#define WS_PRC 0
#define WS_A2C 1024
#define WS_B2C 2048
#define WS_WC 3072
#define WS_EC 4096
#define WS_PRIC 5120
#define WS_A2I 6656
#define WS_B2I 8192
#define WS_WI 9728
#define WS_EI 11264
#define WS_MAX 12800
#define WS_ISTATE 16384
#define WS_VSTATE 32768
#define WS_SENSC 65536

// ---------------- Kernel 0: classify synapses into chain (pre<20) and inter (pre>=20) ----------------
__global__ void build_lists(fp w_syn, fp mu, fp sigma, fp erev, const int* spm,
                            int* prc, float* a2c, float* b2c, float* wc, float* ec,
                            int* pric, float* a2i, float* b2i, float* wi, float* ei,
                            int* maxv) {
    __shared__ int degc[32], degi[32];
    int j = threadIdx.x;
    if (j < 32) {
        int cc = 0, ci = 0;
        for (int i = 0; i < 32; ++i) {
            int p = i * 32 + j;
            if (spm[p] != 0) {
                float s = sigma[p];
                float w = w_syn[p];
                if (i < 20) {
                    int sl = j * 8 + cc;
                    prc[sl] = i; a2c[sl] = -s * L2E; b2c[sl] = s * mu[p] * L2E;
                    wc[sl] = w; ec[sl] = w * erev[p];
                    ++cc;
                } else {
                    int sl = j * 12 + ci;
                    pric[sl] = i - 20; a2i[sl] = -s * L2E; b2i[sl] = s * mu[p] * L2E;
                    wi[sl] = w; ei[sl] = w * erev[p];
                    ++ci;
                }
            }
        }
        for (int c = cc; c < 8; ++c) { int sl = j*8+c; prc[sl]=0; a2c[sl]=0; b2c[sl]=0; wc[sl]=0; ec[sl]=0; }
        for (int c = ci; c < 12; ++c){ int sl = j*12+c; pric[sl]=0; a2i[sl]=0; b2i[sl]=0; wi[sl]=0; ei[sl]=0; }
        degc[j] = cc; degi[j] = ci;
    }
    __syncthreads();
    if (j == 0) {
        int mc = 0, mi = 0;
        for (int k = 0; k < 32; ++k) { mc = max(mc, degc[k]); mi = max(mi, degi[k]); }
        maxv[0] = mc; maxv[1] = mi;
    }
}

// ---------------- Kernel A: dense stack + sensory gate sums (folded pn', pd') ----------------
__global__ __launch_bounds__(256) void dense_sens(
    fp x, fp d1w, fp d1b, fp d2w, fp d2b, fp iw, fp ib,
    fp sw, fp smu, fp ssg, fp serev, const int* smask,
    fp gleak, fp vleak, fp cm,
    float2* sensC, int t0, int CT) {
    __shared__ float W1s[256], b1s[128], W2s[4096], b2s[32], iws[32], ibs[32];
    __shared__ float gss[1024], gnm[1024], gwm[1024], gwe[1024];
    __shared__ float num0[32], den0[32];
    __shared__ float hbuf[8][128];
    __shared__ float ibuf[8][32];
    int tid = threadIdx.x;
    if (tid < 256) W1s[tid] = d1w[tid];
    if (tid < 128) b1s[tid] = d1b[tid];
    for (int p = tid; p < 4096; p += 256) W2s[p] = d2w[p];
    if (tid < 32) {
        b2s[tid] = d2b[tid]; iws[tid] = iw[tid]; ibs[tid] = ib[tid];
        float gl = gleak[tid];
        num0[tid] = gl * vleak[tid];
        den0[tid] = cm[tid] * (float)NUNF + gl + 1e-8f;
    }
    for (int p = tid; p < 1024; p += 256) {
        float s = ssg[p];
        float wv = sw[p];
        gss[p] = -s * L2E;
        gnm[p] = s * smu[p] * L2E;
        gwm[p] = wv * (float)smask[p];
        gwe[p] = wv * serev[p];
    }
    __syncthreads();
    int g = tid >> 5, j = tid & 31;
    const float2* x2 = (const float2*)x;
    int niters = CT * 32;
    for (int itg = blockIdx.x; itg < niters; itg += gridDim.x) {
        int cg = itg * 8 + g;             // cg = lt*256 + b
        int lt = cg >> 8, b = cg & 255;
        int t = t0 + lt;
        float2 xv = x2[b * NT + t];
#pragma unroll
        for (int r = 0; r < 4; ++r) {
            int k = j + 32 * r;
            float hk = fmaf(xv.y, W1s[128 + k], fmaf(xv.x, W1s[k], b1s[k]));
            hbuf[g][k] = hk > 0.f ? hk : 0.f;
        }
        float acc = b2s[j];
#pragma unroll 8
        for (int k = 0; k < 128; ++k) acc = fmaf(hbuf[g][k], W2s[k * 32 + j], acc);
        ibuf[g][j] = fmaf(acc, iws[j], ibs[j]);
        float wn = num0[j], wd = den0[j];
        for (int i = 0; i < 32; ++i) {
            int p = i * 32 + j;
            float xg = fmaf(ibuf[g][i], gss[p], gnm[p]);
            float sg = frcp(1.f + ex2(xg));
            wn = fmaf(gwe[p], sg, wn);
            wd = fmaf(gwm[p], sg, wd);
        }
        sensC[cg * 32 + j] = make_float2(wn, wd);
    }
}

// ---------------- Kernel B: inter-neuron affine scan over t ----------------
__global__ __launch_bounds__(64) void inter_scan(const float2* __restrict__ sensC, fp cm,
                                                 float4* interP, float* interState,
                                                 int t0, int CT) {
    int lane = threadIdx.x;
    int p = lane & 15, q = lane >> 4;
    int b = blockIdx.x * 4 + q;
    bool act = p < 12;
    int j = 20 + (act ? p : 0);
    float cmt = cm[j] * (float)NUNF;
    float v = (t0 == 0) ? 0.f : (act ? interState[b * 12 + p] : 0.f);
    const float2* sp = sensC + b * 32 + j;
    float4* op = interP + b * 12 + (act ? p : 0);
    int lt = 0;
    for (; lt + 8 <= CT; lt += 8) {
        float2 sv[8];
#pragma unroll
        for (int k = 0; k < 8; ++k) sv[k] = sp[(size_t)(lt + k) * (NB * 32)];
#pragma unroll
        for (int k = 0; k < 8; ++k) {
            float r = frcp(sv[k].y);
            float A = cmt * r, B = sv[k].x * r;
            if (act) op[(size_t)(lt + k) * (NB * 12)] = make_float4(v, A, B, 0.f);
#pragma unroll
            for (int u = 0; u < NUNF; ++u) v = fmaf(A, v, B);
        }
    }
    for (; lt < CT; ++lt) {
        float2 s = sp[(size_t)lt * (NB * 32)];
        float r = frcp(s.y);
        float A = cmt * r, B = s.x * r;
        if (act) op[(size_t)lt * (NB * 12)] = make_float4(v, A, B, 0.f);
#pragma unroll
        for (int u = 0; u < NUNF; ++u) v = fmaf(A, v, B);
    }
    if (act) interState[b * 12 + p] = v;
}

// ---------------- Kernel C: command/motor chain scan ----------------
template <int MIC>
__device__ __forceinline__ void prep_sums(float (&pn)[6], float (&pd)[6], float2 sC,
                                          const float4 (&ip)[MIC], const float (&Ai)[MIC],
                                          const float (&Bi)[MIC], const float (&Wi)[MIC],
                                          const float (&Ei)[MIC]) {
#pragma unroll
    for (int u = 0; u < 6; ++u) { pn[u] = sC.x; pd[u] = sC.y; }
#pragma unroll
    for (int s = 0; s < MIC; ++s) {
        float vi = ip[s].x, A = ip[s].y, B = ip[s].z;
#pragma unroll
        for (int u = 0; u < 6; ++u) {
            float g = frcp(1.f + ex2(fmaf(Ai[s], vi, Bi[s])));
            pn[u] = fmaf(Ei[s], g, pn[u]);
            pd[u] = fmaf(Wi[s], g, pd[u]);
            vi = fmaf(A, vi, B);
        }
    }
}

template <int MC, int MIC>
__device__ void cscan(const float2* __restrict__ sensC, const float4* __restrict__ interP,
                      fp cm, const int* prc, const float* a2c, const float* b2c,
                      const float* wc, const float* ec,
                      const int* pric, const float* a2i, const float* b2i,
                      const float* wi, const float* ei,
                      float* vstate, fp ow, fp ob, int t0, int CT, float* out) {
    int lane = threadIdx.x;
    int j = lane & 31;
    int b = blockIdx.x * 2 + (lane >> 5);
    float cm_t = cm[j] * (float)NUNF;
    int apc[MC]; float Ac[MC], Bc[MC], Wc[MC], Ec[MC];
#pragma unroll
    for (int s = 0; s < MC; ++s) {
        int sl = j * 8 + s;
        apc[s] = ((lane & 32) | prc[sl]) << 2;
        Ac[s] = a2c[sl]; Bc[s] = b2c[sl]; Wc[s] = wc[sl]; Ec[s] = ec[sl];
    }
    int ipi[MIC]; float Ai[MIC], Bi[MIC], Wi[MIC], Ei[MIC];
#pragma unroll
    for (int s = 0; s < MIC; ++s) {
        int sl = j * 12 + s;
        ipi[s] = pric[sl];
        Ai[s] = a2i[sl]; Bi[s] = b2i[sl]; Wi[s] = wi[sl]; Ei[s] = ei[sl];
    }
    float v = (t0 == 0) ? 0.f : vstate[b * 32 + j];
    // pipeline: load t, prep t, load t+1; loop: chain(t) | prep(t+1) | load(t+2)
    float2 sC = sensC[(size_t)b * 32 + j];
    float4 ip[MIC];
#pragma unroll
    for (int s = 0; s < MIC; ++s) ip[s] = interP[(size_t)b * 12 + ipi[s]];
    float pn[6], pd[6];
    prep_sums<MIC>(pn, pd, sC, ip, Ai, Bi, Wi, Ei);
    int tn = (CT > 1) ? 1 : 0;
    sC = sensC[((size_t)tn * NB + b) * 32 + j];
#pragma unroll
    for (int s = 0; s < MIC; ++s) ip[s] = interP[((size_t)tn * NB + b) * 12 + ipi[s]];
    for (int t = 0; t < CT; ++t) {
        // ---- dependent chain: 6 unfolds ----
#pragma unroll
        for (int u = 0; u < 6; ++u) {
            float vp[MC];
#pragma unroll
            for (int s = 0; s < MC; ++s)
                vp[s] = __int_as_float(__builtin_amdgcn_ds_bpermute(apc[s], __float_as_int(v)));
            float wn = pn[u], wd = pd[u];
#pragma unroll
            for (int s = 0; s < MC; ++s) {
                float g = frcp(1.f + ex2(fmaf(Ac[s], vp[s], Bc[s])));
                wn = fmaf(Ec[s], g, wn);
                wd = fmaf(Wc[s], g, wd);
            }
            v = fmaf(cm_t, v, wn) * frcp(wd);
        }
        // ---- prep t+1 (independent of chain; compiler interleaves) ----
        float npn[6], npd[6];
        prep_sums<MIC>(npn, npd, sC, ip, Ai, Bi, Wi, Ei);
#pragma unroll
        for (int u = 0; u < 6; ++u) { pn[u] = npn[u]; pd[u] = npd[u]; }
        // ---- issue loads for t+2 ----
        int t2 = t + 2; if (t2 > CT - 1) t2 = CT - 1;
        sC = sensC[((size_t)t2 * NB + b) * 32 + j];
#pragma unroll
        for (int s = 0; s < MIC; ++s) ip[s] = interP[((size_t)t2 * NB + b) * 12 + ipi[s]];
    }
    vstate[b * 32 + j] = v;
    if (t0 + CT == NT && j == 0) out[b] = fmaf(v, ow[0], ob[0]);
}

__global__ __launch_bounds__(64) void cmd_scan(
    const float2* __restrict__ sensC, const float4* __restrict__ interP, fp cm,
    const int* prc, const float* a2c, const float* b2c, const float* wc, const float* ec,
    const int* pric, const float* a2i, const float* b2i, const float* wi, const float* ei,
    const int* maxv, float* vstate, fp ow, fp ob, int t0, int CT, float* out) {
    int mc = maxv[0], mi = maxv[1];
#define ARGS sensC, interP, cm, prc, a2c, b2c, wc, ec, pric, a2i, b2i, wi, ei, vstate, ow, ob, t0, CT, out
    if (mc <= 4) {
        if (mi <= 4)      cscan<4, 4>(ARGS);
        else if (mi <= 6) cscan<4, 6>(ARGS);
        else if (mi <= 8) cscan<4, 8>(ARGS);
        else              cscan<4, 12>(ARGS);
    } else {
        if (mi <= 6)      cscan<6, 6>(ARGS);
        else if (mi <= 8) cscan<6, 8>(ARGS);
        else              cscan<6, 12>(ARGS);
    }
#undef ARGS
}

extern "C" void kernel_launch(void* const* d_in, const int* in_sizes, int n_in,
                              void* d_out, int out_size, void* d_ws, size_t ws_size,
                              hipStream_t stream) {
    fp x     = (fp)d_in[0];
    fp d1w   = (fp)d_in[1];
    fp d1b   = (fp)d_in[2];
    fp d2w   = (fp)d_in[3];
    fp d2b   = (fp)d_in[4];
    fp iw    = (fp)d_in[5];
    fp ib    = (fp)d_in[6];
    fp ow    = (fp)d_in[7];
    fp ob    = (fp)d_in[8];
    fp gleak = (fp)d_in[9];
    fp vleak = (fp)d_in[10];
    fp cm    = (fp)d_in[11];
    fp wsyn  = (fp)d_in[12];
    fp mu    = (fp)d_in[13];
    fp sigma = (fp)d_in[14];
    fp erev  = (fp)d_in[15];
    fp sw    = (fp)d_in[16];
    fp smu   = (fp)d_in[17];
    fp ssg   = (fp)d_in[18];
    fp serev = (fp)d_in[19];
    const int* spm   = (const int*)d_in[20];
    const int* smask = (const int*)d_in[21];

    char* wsb = (char*)d_ws;
    int*   prc   = (int*)  (wsb + WS_PRC);
    float* a2c   = (float*)(wsb + WS_A2C);
    float* b2c   = (float*)(wsb + WS_B2C);
    float* wc    = (float*)(wsb + WS_WC);
    float* ec    = (float*)(wsb + WS_EC);
    int*   pric  = (int*)  (wsb + WS_PRIC);
    float* a2i   = (float*)(wsb + WS_A2I);
    float* b2i   = (float*)(wsb + WS_B2I);
    float* wi    = (float*)(wsb + WS_WI);
    float* ei    = (float*)(wsb + WS_EI);
    int*   maxv  = (int*)  (wsb + WS_MAX);
    float* istate = (float*)(wsb + WS_ISTATE);
    float* vstate = (float*)(wsb + WS_VSTATE);

    // chunk size: sensC = CT*64KB, interP = CT*48KB after 64KB base
    size_t per_t = 65536 + 49152;
    int CT = 1;
    if (ws_size > WS_SENSC + per_t) {
        size_t m = (ws_size - WS_SENSC) / per_t;
        int ct = 1;
        while (ct < NT && (size_t)(ct * 2) <= m) ct *= 2;
        CT = ct;
    }
    float2* sensC  = (float2*)(wsb + WS_SENSC);
    float4* interP = (float4*)(wsb + WS_SENSC + (size_t)CT * 65536);

    build_lists<<<1, 64, 0, stream>>>(wsyn, mu, sigma, erev, spm,
                                      prc, a2c, b2c, wc, ec,
                                      pric, a2i, b2i, wi, ei, maxv);

    int nch = NT / CT;
    for (int c = 0; c < nch; ++c) {
        int t0 = c * CT;
        int blocks = CT * 32; if (blocks > 1024) blocks = 1024;
        dense_sens<<<blocks, 256, 0, stream>>>(x, d1w, d1b, d2w, d2b, iw, ib,
                                               sw, smu, ssg, serev, smask,
                                               gleak, vleak, cm, sensC, t0, CT);
        inter_scan<<<64, 64, 0, stream>>>(sensC, cm, interP, istate, t0, CT);
        cmd_scan<<<NB / 2, 64, 0, stream>>>(sensC, interP, cm,
                                            prc, a2c, b2c, wc, ec,
                                            pric, a2i, b2i, wi, ei,
                                            maxv, vstate, ow, ob, t0, CT, (float*)d_out);
    }
}